// Round 8
// baseline (405.851 us; speedup 1.0000x reference)
//
#include <hip/hip_runtime.h>
#include <hip/hip_bf16.h>
#include <stdint.h>

typedef __attribute__((ext_vector_type(8))) short bf16x8;
typedef __attribute__((ext_vector_type(4))) float f32x4;
typedef __attribute__((ext_vector_type(16))) float f32x16;
typedef unsigned short u16;
typedef unsigned int u32;

constexpr int T  = 4096;
constexpr int C  = 512;
constexpr int H  = 8;
constexpr int CH = 64;
constexpr float EPS = 1e-6f;
constexpr float QKS   = 0.35355339059327378f;                       // 64^-0.25
constexpr float QKS_Q = 0.35355339059327378f * 1.4426950408889634f; // fold log2e into q

__device__ __forceinline__ float bf2f(u16 u) {
    union { unsigned int i; float f; } v; v.i = ((unsigned int)u) << 16; return v.f;
}
__device__ __forceinline__ u16 f2bf(float f) {
    union { float f; unsigned int i; } v; v.f = f;
    return (u16)((v.i + 0x7FFFu + ((v.i >> 16) & 1u)) >> 16);
}
__device__ __forceinline__ u32 pk2bf(float a, float b) {
    __hip_bfloat162 h = __float22bfloat162_rn(make_float2(a, b));
    u32 r; __builtin_memcpy(&r, &h, 4); return r;
}
__device__ __forceinline__ float ldin(const void* p, int i, int f32) {
    return f32 ? ((const float*)p)[i] : bf2f(((const u16*)p)[i]);
}
__device__ __forceinline__ void async16(const void* g, void* l) {
    __builtin_amdgcn_global_load_lds(
        (const __attribute__((address_space(1))) void*)g,
        (__attribute__((address_space(3))) void*)l,
        16, 0, 0);
}
// pack hi16(a)|hi16(b)<<16 in ONE v_perm_b32 (truncating bf16 pack)
__device__ __forceinline__ u32 pktrunc(float a, float b) {
    u32 ua = __float_as_uint(a), ub = __float_as_uint(b);
    return __builtin_amdgcn_perm(ub, ua, 0x07060302u);
}

// ---------------- kernel 1: per-block group partial sums (+ dtype flag), no atomics ------
__global__ void k_stats1(const void* x, float* gs2, int* flag) {
    int b = blockIdx.x, tid = threadIdx.x;          // 128 blocks, 32 rows each
    int lane = tid & 63, w = tid >> 6;
    __shared__ int cnt;
    __shared__ float red[4][32][2];
    if (tid == 0) cnt = 0;
    __syncthreads();
    const u16* u = (const u16*)x;
    int huge = 0;
    for (int i = tid; i < 1024; i += 256) {
        float a = fabsf(bf2f(u[i]));
        if (!(a < 1e4f)) huge++;
    }
    if (huge) atomicAdd(&cnt, huge);
    __syncthreads();
    int f32 = (cnt >= 8) ? 1 : 0;
    if (b == 0 && tid == 0) *flag = f32;
    float s1 = 0.f, s2 = 0.f;
    if (f32) {
        const float4* xp = (const float4*)x + b * 4096;
        #pragma unroll
        for (int i = 0; i < 16; i++) {
            float4 v = xp[i * 256 + tid];
            s1 += (v.x + v.y) + (v.z + v.w);
            s2 += (v.x*v.x + v.y*v.y) + (v.z*v.z + v.w*v.w);
        }
        s1 += __shfl_xor(s1, 1); s2 += __shfl_xor(s2, 1);
        s1 += __shfl_xor(s1, 2); s2 += __shfl_xor(s2, 2);
        if ((lane & 3) == 0) {
            int gl = (lane >> 2) + 16 * (w & 1);
            red[w][gl][0] = s1; red[w][gl][1] = s2;
        }
        __syncthreads();
        if (tid < 32) {
            int g = tid, w0 = (g < 16) ? 0 : 1;
            gs2[b * 64 + g * 2]     = red[w0][g][0] + red[w0 + 2][g][0];
            gs2[b * 64 + g * 2 + 1] = red[w0][g][1] + red[w0 + 2][g][1];
        }
    } else {
        const uint4* xp = (const uint4*)x + b * 2048;
        #pragma unroll
        for (int i = 0; i < 8; i++) {
            uint4 v = xp[i * 256 + tid];
            float f[8] = { bf2f((u16)(v.x&0xffff)), bf2f((u16)(v.x>>16)),
                           bf2f((u16)(v.y&0xffff)), bf2f((u16)(v.y>>16)),
                           bf2f((u16)(v.z&0xffff)), bf2f((u16)(v.z>>16)),
                           bf2f((u16)(v.w&0xffff)), bf2f((u16)(v.w>>16)) };
            #pragma unroll
            for (int j = 0; j < 8; j++) { s1 += f[j]; s2 += f[j]*f[j]; }
        }
        s1 += __shfl_xor(s1, 1); s2 += __shfl_xor(s2, 1);
        if ((lane & 1) == 0) { red[w][lane >> 1][0] = s1; red[w][lane >> 1][1] = s2; }
        __syncthreads();
        if (tid < 32) {
            int g = tid;
            gs2[b * 64 + g * 2]     = red[0][g][0]+red[1][g][0]+red[2][g][0]+red[3][g][0];
            gs2[b * 64 + g * 2 + 1] = red[0][g][1]+red[1][g][1]+red[2][g][1]+red[3][g][1];
        }
    }
}

// ---------------- kernel 2: fused normalize (blocks 0..1023) + weight transpose (1024..1279) --
__global__ void k_fuse(const void* x, const float* __restrict__ gs2,
                       const void* gsc, const void* gbi, const void* wq,
                       u16* __restrict__ xn, u16* __restrict__ wt,
                       const int* __restrict__ flag) {
    int bx = blockIdx.x, tid = threadIdx.x;
    int f32 = *flag;
    if (bx < 1024) {
        __shared__ float sred[64];
        if (tid < 64) {                              // reduce 128 block-partials (L2-hot)
            float a0 = 0.f, a1 = 0.f, a2 = 0.f, a3 = 0.f;
            const float* p = gs2 + tid;
            #pragma unroll
            for (int b = 0; b < 32; b++) {
                a0 += p[(4*b + 0) * 64];
                a1 += p[(4*b + 1) * 64];
                a2 += p[(4*b + 2) * 64];
                a3 += p[(4*b + 3) * 64];
            }
            sred[tid] = (a0 + a1) + (a2 + a3);
        }
        __syncthreads();
        int idx = (bx * 256 + tid) * 8;
        int c = idx & (C - 1);
        int g = c >> 4;
        float mean = sred[2 * g] * (1.0f / 65536.0f);
        float var  = sred[2 * g + 1] * (1.0f / 65536.0f) - mean * mean;
        float rstd = rsqrtf(var + EPS);
        float v[8];
        if (f32) {
            float4 x0 = *(const float4*)((const float*)x + idx);
            float4 x1 = *(const float4*)((const float*)x + idx + 4);
            v[0]=x0.x; v[1]=x0.y; v[2]=x0.z; v[3]=x0.w;
            v[4]=x1.x; v[5]=x1.y; v[6]=x1.z; v[7]=x1.w;
        } else {
            uint4 u = *(const uint4*)((const u16*)x + idx);
            v[0]=bf2f((u16)(u.x&0xffff)); v[1]=bf2f((u16)(u.x>>16));
            v[2]=bf2f((u16)(u.y&0xffff)); v[3]=bf2f((u16)(u.y>>16));
            v[4]=bf2f((u16)(u.z&0xffff)); v[5]=bf2f((u16)(u.z>>16));
            v[6]=bf2f((u16)(u.w&0xffff)); v[7]=bf2f((u16)(u.w>>16));
        }
        float r[8];
        #pragma unroll
        for (int i = 0; i < 8; i++) {
            float a = rstd * ldin(gsc, c + i, f32);
            r[i] = v[i] * a + (ldin(gbi, c + i, f32) - mean * a);
        }
        uint4 o;
        o.x = pk2bf(r[0], r[1]); o.y = pk2bf(r[2], r[3]);
        o.z = pk2bf(r[4], r[5]); o.w = pk2bf(r[6], r[7]);
        *(uint4*)(xn + idx) = o;
    } else {
        // transpose wq[k][col] -> wt[m][k], m = j*512+cc, col = 3*cc+j.
        __shared__ u16 Wl[48][64];
        int b = bx - 1024;                           // 0..255
        int k0 = (b >> 5) * 64, c0 = (b & 31) * 48;
        #pragma unroll
        for (int it = 0; it < 3; it++) {
            int u_ = it * 256 + tid;                 // 768 units = 64 rows x 12 col-quads
            int r = u_ / 12, cu = u_ % 12;
            int gi = (k0 + r) * 1536 + c0 + cu * 4;
            float v0, v1, v2, v3;
            if (f32) {
                float4 t4 = *(const float4*)((const float*)wq + gi);
                v0 = t4.x; v1 = t4.y; v2 = t4.z; v3 = t4.w;
            } else {
                uint2 t2 = *(const uint2*)((const u16*)wq + gi);
                v0 = bf2f((u16)(t2.x & 0xffff)); v1 = bf2f((u16)(t2.x >> 16));
                v2 = bf2f((u16)(t2.y & 0xffff)); v3 = bf2f((u16)(t2.y >> 16));
            }
            Wl[cu*4+0][r] = f2bf(v0); Wl[cu*4+1][r] = f2bf(v1);
            Wl[cu*4+2][r] = f2bf(v2); Wl[cu*4+3][r] = f2bf(v3);
        }
        __syncthreads();
        #pragma unroll
        for (int it = 0; it < 2; it++) {
            int u_ = it * 256 + tid;                 // 384 units = 48 m-rows x 8 k-chunks
            if (u_ < 384) {
                int mrow = u_ >> 3, kc = u_ & 7;
                int j = mrow >> 4, cci = mrow & 15;
                int m = j * 512 + (c0 / 3) + cci;
                int cl = 3 * cci + j;
                uint4 val = *(const uint4*)&Wl[cl][kc * 8];
                *(uint4*)(wt + m * 512 + k0 + kc * 8) = val;
            }
        }
    }
}

// ---------------- kernel 3: QKV GEMM, 64x128 tiles, BK=64, double-buffered ----------------
// V epilogue stores vt with key-index bits 2<->3 swapped (sigma) so k_attn's PV B-operand
// is the lane's own S registers (no cross-lane exchange).
__global__ __launch_bounds__(256) void k_gemm(
    const u16* __restrict__ xn, const u16* __restrict__ wt,
    const void* __restrict__ bq, const int* __restrict__ flag,
    u16* __restrict__ qh, u16* __restrict__ kh, u16* __restrict__ vt)
{
    __shared__ char smem[49152];
    u16* Al = (u16*)smem;                        // 2 x 8KB
    u16* Bl = (u16*)(smem + 16384);              // 2 x 16KB
    int bx = blockIdx.x;
    int bm = bx & 63, bn = bx >> 6;              // 64 x 12
    int tid = threadIdx.x;
    int w = tid >> 6, lane = tid & 63, quad = lane >> 4, l15 = lane & 15;
    f32x4 acc[4][2] = {};
    const u16* Ag = xn + bm * 64 * 512;
    const u16* Bg = wt + bn * 128 * 512;

    #pragma unroll
    for (int i = 0; i < 2; i++) {
        int L = i * 256 + tid, row = L >> 3, cc = ((L & 7) ^ (row & 7)) * 8;
        async16(Ag + row * 512 + cc, (void*)(Al + L * 8));
    }
    #pragma unroll
    for (int i = 0; i < 4; i++) {
        int L = i * 256 + tid, row = L >> 3, cc = ((L & 7) ^ (row & 7)) * 8;
        async16(Bg + row * 512 + cc, (void*)(Bl + L * 8));
    }

    #pragma unroll
    for (int ki = 0; ki < 8; ki++) {
        __syncthreads();
        if (ki < 7) {
            int kn = (ki + 1) * 64;
            int bo = ((ki + 1) & 1);
            #pragma unroll
            for (int i = 0; i < 2; i++) {
                int L = i * 256 + tid, row = L >> 3, cc = ((L & 7) ^ (row & 7)) * 8;
                async16(Ag + row * 512 + kn + cc, (void*)(Al + bo * 4096 + L * 8));
            }
            #pragma unroll
            for (int i = 0; i < 4; i++) {
                int L = i * 256 + tid, row = L >> 3, cc = ((L & 7) ^ (row & 7)) * 8;
                async16(Bg + row * 512 + kn + cc, (void*)(Bl + bo * 8192 + L * 8));
            }
        }
        const u16* Ab = Al + (ki & 1) * 4096;
        const u16* Bb = Bl + (ki & 1) * 8192;
        #pragma unroll
        for (int kk = 0; kk < 2; kk++) {
            bf16x8 af[4], bfr[2];
            #pragma unroll
            for (int mi = 0; mi < 4; mi++) {
                int row = mi * 16 + l15;
                af[mi] = *(const bf16x8*)(Ab + row * 64 + (((kk * 4 + quad) ^ (row & 7)) * 8));
            }
            #pragma unroll
            for (int ni = 0; ni < 2; ni++) {
                int row = w * 32 + ni * 16 + l15;
                bfr[ni] = *(const bf16x8*)(Bb + row * 64 + (((kk * 4 + quad) ^ (row & 7)) * 8));
            }
            #pragma unroll
            for (int mi = 0; mi < 4; mi++)
                #pragma unroll
                for (int ni = 0; ni < 2; ni++)
                    acc[mi][ni] = __builtin_amdgcn_mfma_f32_16x16x32_bf16(
                        af[mi], bfr[ni], acc[mi][ni], 0, 0, 0);
        }
    }
    int f32 = *flag;
    int t_base = bm * 64;
    int j = bn >> 2;                              // uniform per block
    if (j < 2) {
        u16* dst = j ? kh : qh;
        float s = j ? QKS : QKS_Q;
        #pragma unroll
        for (int ni = 0; ni < 2; ni++) {
            int n = bn * 128 + w * 32 + ni * 16 + l15;
            int r = n & 511, hh = r >> 6, cc = r & 63;
            float bias = ldin(bq, 3 * r + j, f32);
            #pragma unroll
            for (int mi = 0; mi < 4; mi++) {
                int tq = t_base + mi * 16 + quad * 4;
                #pragma unroll
                for (int rg = 0; rg < 4; rg++)
                    dst[(hh * T + tq + rg) * CH + cc] = f2bf((acc[mi][ni][rg] + bias) * s);
            }
        }
    } else {
        __syncthreads();
        u16* Tt = (u16*)smem;
        u16* Tw = Tt + w * 2048;
        int rbase = (bn - 8) * 128 + w * 32;
        int hh = rbase >> 6;                      // uniform per wave
        #pragma unroll
        for (int ni = 0; ni < 2; ni++) {
            int r = rbase + ni * 16 + l15;
            float bias = ldin(bq, 3 * (r & 511) + 2, f32);
            int rl = ni * 16 + l15;
            #pragma unroll
            for (int mi = 0; mi < 4; mi++) {
                uint2 pv;
                pv.x = pk2bf(acc[mi][ni][0] + bias, acc[mi][ni][1] + bias);
                pv.y = pk2bf(acc[mi][ni][2] + bias, acc[mi][ni][3] + bias);
                int cs = (mi * 2 + (quad >> 1)) ^ (rl & 7);
                *(uint2*)((u32*)Tw + rl * 32 + cs * 4 + (quad & 1) * 2) = pv;
            }
        }
        // sigma-permuted store: physical 4-key group A (chunk g&~1) + group B (chunk (g&~1)+1),
        // half offset (g&1)*4, land at target run g*8 (bits 2,3 of key index swapped).
        int cc_hi = (w & 1) * 32;
        #pragma unroll
        for (int rr = 0; rr < 4; rr++) {
            int rl = rr * 8 + (lane >> 3);
            int g = lane & 7;
            int cA = (g & ~1) ^ (rl & 7);
            int cB = ((g & ~1) + 1) ^ (rl & 7);
            int ofs = (g & 1) * 4;
            uint2 a = *(const uint2*)(Tw + rl * 64 + cA * 8 + ofs);
            uint2 b = *(const uint2*)(Tw + rl * 64 + cB * 8 + ofs);
            *(uint4*)(vt + (hh * CH + cc_hi + rl) * T + t_base + g * 8) =
                make_uint4(a.x, a.y, b.x, b.y);
        }
    }
}

// ---------------- kernel 4: flash attention v8 ----------
// grid 1024 = (h, qb, ks): 128 q x 1024 keys; single barrier/iter; K+V dbuf.
// S^T 32x32x16 -> P B-frags are the lane's OWN packed S regs (vt key-permuted).
// Split-K merge fused: last-arriving ks block normalizes + writes out.
__global__ __launch_bounds__(256, 4) void k_attn(
    const u16* __restrict__ qh, const u16* __restrict__ kh,
    const u16* __restrict__ vt, float* __restrict__ opart, float* __restrict__ ls,
    int* __restrict__ tick, void* __restrict__ out, const int* __restrict__ flag)
{
    __shared__ char lds[32768];
    u16* K0 = (u16*)lds;                         // 2 x 8KB K dbuf
    u16* V0 = (u16*)(lds + 16384);               // 2 x 8KB V dbuf
    int bx = blockIdx.x;
    int h = bx >> 7, qb = (bx >> 2) & 31, ks = bx & 3;
    int t0 = qb * 128;
    int tid = threadIdx.x;
    int w = tid >> 6, lane = tid & 63;
    int l31 = lane & 31, hi = lane >> 5;

    const u16* Kg = kh + (h * T + ks * 1024) * CH;
    const u16* Vg = vt + h * CH * T + ks * 1024;

    int L0 = tid,       r0 = L0 >> 3, c0 = ((L0 & 7) ^ (r0 & 7)) * 8;
    int L1 = 256 + tid, r1 = L1 >> 3, c1 = ((L1 & 7) ^ (r1 & 7)) * 8;
    const u16* kp0 = Kg + r0 * CH + c0;
    const u16* kp1 = Kg + r1 * CH + c1;
    const u16* vp0 = Vg + r0 * T + c0;
    const u16* vp1 = Vg + r1 * T + c1;

    int off[2][4];
    #pragma unroll
    for (int rt = 0; rt < 2; rt++)
        #pragma unroll
        for (int c = 0; c < 4; c++) {
            int row = rt * 32 + l31;
            off[rt][c] = row * 64 + (((2 * c + hi) ^ (row & 7)) * 8);
        }

    bf16x8 bq[4];
    {
        const u16* qrow = qh + (h * T + t0 + w * 32 + l31) * CH;
        #pragma unroll
        for (int ksi = 0; ksi < 4; ksi++)
            bq[ksi] = *(const bf16x8*)(qrow + ksi * 16 + hi * 8);
    }

    async16(kp0, (void*)(K0 + L0 * 8));
    async16(kp1, (void*)(K0 + L1 * 8));
    async16(vp0, (void*)(V0 + L0 * 8));
    async16(vp1, (void*)(V0 + L1 * 8));

    f32x16 o[2] = {};
    float lsum = 0.f;

    for (int kt = 0; kt < 16; kt++) {
        int par = (kt & 1) * 4096;
        const u16* Kc = K0 + par;
        const u16* Vc = V0 + par;
        __syncthreads();                         // tile kt staged & visible; kt-1 reads done
        if (kt < 15) {                           // prefetch kt+1, drains at NEXT barrier
            int nx = ((kt + 1) & 1) * 4096;
            int ko = (kt + 1) * 64 * CH;
            int vo = (kt + 1) * 64;
            async16(kp0 + ko, (void*)(K0 + nx + L0 * 8));
            async16(kp1 + ko, (void*)(K0 + nx + L1 * 8));
            async16(vp0 + vo, (void*)(V0 + nx + L0 * 8));
            async16(vp1 + vo, (void*)(V0 + nx + L1 * 8));
        }
        // S^T = K . Q^T -> D[key][q]
        f32x16 sa[2] = {};
        #pragma unroll
        for (int t = 0; t < 2; t++)
            #pragma unroll
            for (int ksi = 0; ksi < 4; ksi++) {
                bf16x8 aK = *(const bf16x8*)(Kc + off[t][ksi]);
                sa[t] = __builtin_amdgcn_mfma_f32_32x32x16_bf16(aK, bq[ksi], sa[t], 0, 0, 0);
            }
        // softmax (exp2 domain) + DIRECT B-frag pack (vt is sigma-permuted: no exchange)
        u32 bp[4][4];
        #pragma unroll
        for (int t = 0; t < 2; t++) {
            float rs = 0.f;
            #pragma unroll
            for (int pi = 0; pi < 8; pi++) {
                float e0 = exp2f(sa[t][2 * pi]);
                float e1 = exp2f(sa[t][2 * pi + 1]);
                rs += e0 + e1;
                bp[2 * t + (pi >> 2)][pi & 3] = pktrunc(e0, e1);
            }
            lsum += rs;
        }
        // O^T += V^T . P -> D[d][q]
        #pragma unroll
        for (int dt = 0; dt < 2; dt++)
            #pragma unroll
            for (int kst = 0; kst < 4; kst++) {
                bf16x8 aV = *(const bf16x8*)(Vc + off[dt][kst]);
                bf16x8 bpv;
                __builtin_memcpy(&bpv, bp[kst], 16);
                o[dt] = __builtin_amdgcn_mfma_f32_32x32x16_bf16(aV, bpv, o[dt], 0, 0, 0);
            }
    }
    lsum += __shfl_xor(lsum, 32);                // merge key-halves (same q)

    __syncthreads();                             // all waves done with K/V LDS
    float* Sw = (float*)(lds + w * 6144);        // per-wave strip: [32 q][33] fp32
    int qg = t0 + w * 32;
    int q2 = lane >> 1, half = lane & 1;
    #pragma unroll
    for (int dt = 0; dt < 2; dt++) {
        #pragma unroll
        for (int reg = 0; reg < 16; reg++) {
            int dl = (reg & 3) + 8 * (reg >> 2) + 4 * hi;
            Sw[l31 * 33 + dl] = o[dt][reg];
        }
        const float* src = Sw + q2 * 33 + half * 16;
        float* dst = opart + ((ks * 8 + h) * T + qg + q2) * 64 + dt * 32 + half * 16;
        #pragma unroll
        for (int i = 0; i < 4; i++)
            *(f32x4*)(dst + i * 4) = *(const f32x4*)(src + i * 4);
    }
    if (hi == 0) ls[(ks * 8 + h) * T + qg + l31] = lsum;

    // ---- fused split-K merge: last ks block for (h,qb) normalizes + writes out ----
    __threadfence();                             // release opart/ls
    __shared__ int rank_s;
    if (tid == 0) rank_s = atomicAdd(&tick[h * 32 + qb], 1);
    __syncthreads();
    if (rank_s != 3) return;
    __threadfence();                             // acquire other blocks' writes
    int f32v = *flag;
    int q = tid >> 1, dh = (tid & 1) * 32;       // 128 q x 2 d-halves
    int ht = h * T + t0 + q;
    float inv = 1.0f / (ls[ht] + ls[32768 + ht] + ls[65536 + ht] + ls[98304 + ht]);
    const float* s0 = opart + (size_t)ht * 64 + dh;
    int gbase = (t0 + q) * C + h * CH + dh;
    #pragma unroll
    for (int i = 0; i < 8; i++) {
        f32x4 v = *(const f32x4*)(s0 + i * 4);
        v += *(const f32x4*)(s0 + 2097152 + i * 4);
        v += *(const f32x4*)(s0 + 4194304 + i * 4);
        v += *(const f32x4*)(s0 + 6291456 + i * 4);
        v *= inv;
        if (f32v) {
            *(f32x4*)((float*)out + gbase + i * 4) = v;
        } else {
            *(uint2*)((u16*)out + gbase + i * 4) =
                make_uint2(pk2bf(v[0], v[1]), pk2bf(v[2], v[3]));
        }
    }
}

extern "C" void kernel_launch(void* const* d_in, const int* in_sizes, int n_in,
                              void* d_out, int out_size, void* d_ws, size_t ws_size,
                              hipStream_t stream) {
    const void* x   = d_in[0];
    const void* gsc = d_in[1];
    const void* gbi = d_in[2];
    const void* wq  = d_in[3];
    const void* bq  = d_in[4];
    char* ws = (char*)d_ws;
    int*   flag = (int*)ws;                          // 4 B
    char* base = ws + 8192;
    u16* qh = (u16*)(base);                          // 4 MB
    u16* kh = (u16*)(base + 4194304);                // 4 MB
    u16* vt = (u16*)(base + 8388608);                // 4 MB (sigma key-permuted)
    u16* xn = (u16*)(base + 12582912);               // 4 MB   (dead after k_gemm)
    u16* wt = (u16*)(base + 16777216);               // 1.5 MB (dead after k_gemm)
    float* opart = (float*)(base + 12582912);        // 32 MB, overlaps xn/wt
    float* ls    = (float*)(base + 46137344);        // 512 KB
    float* gs2   = (float*)(base + 46661632);        // 32 KB per-block group partials
    int*   tick  = (int*)(base + 46694400);          // 1 KB split-K arrival counters

    hipMemsetAsync(tick, 0, 1024, stream);
    hipLaunchKernelGGL(k_stats1, dim3(128),  dim3(256), 0, stream, x, gs2, flag);
    hipLaunchKernelGGL(k_fuse,   dim3(1280), dim3(256), 0, stream, x, gs2, gsc, gbi, wq, xn, wt, flag);
    hipLaunchKernelGGL(k_gemm,   dim3(768),  dim3(256), 0, stream, xn, wt, bq, flag, qh, kh, vt);
    hipLaunchKernelGGL(k_attn,   dim3(1024), dim3(256), 0, stream, qh, kh, vt, opart, ls, tick, d_out, flag);
}

// Round 9
// 160.071 us; speedup vs baseline: 2.5354x; 2.5354x over previous
//
#include <hip/hip_runtime.h>
#include <hip/hip_bf16.h>
#include <stdint.h>

typedef __attribute__((ext_vector_type(8))) short bf16x8;
typedef __attribute__((ext_vector_type(4))) float f32x4;
typedef __attribute__((ext_vector_type(16))) float f32x16;
typedef unsigned short u16;
typedef unsigned int u32;

constexpr int T  = 4096;
constexpr int C  = 512;
constexpr int H  = 8;
constexpr int CH = 64;
constexpr float EPS = 1e-6f;
constexpr float QKS   = 0.35355339059327378f;                       // 64^-0.25
constexpr float QKS_Q = 0.35355339059327378f * 1.4426950408889634f; // fold log2e into q

__device__ __forceinline__ float bf2f(u16 u) {
    union { unsigned int i; float f; } v; v.i = ((unsigned int)u) << 16; return v.f;
}
__device__ __forceinline__ u16 f2bf(float f) {
    union { float f; unsigned int i; } v; v.f = f;
    return (u16)((v.i + 0x7FFFu + ((v.i >> 16) & 1u)) >> 16);
}
__device__ __forceinline__ u32 pk2bf(float a, float b) {
    __hip_bfloat162 h = __float22bfloat162_rn(make_float2(a, b));
    u32 r; __builtin_memcpy(&r, &h, 4); return r;
}
__device__ __forceinline__ float ldin(const void* p, int i, int f32) {
    return f32 ? ((const float*)p)[i] : bf2f(((const u16*)p)[i]);
}
__device__ __forceinline__ void async16(const void* g, void* l) {
    __builtin_amdgcn_global_load_lds(
        (const __attribute__((address_space(1))) void*)g,
        (__attribute__((address_space(3))) void*)l,
        16, 0, 0);
}
// pack hi16(a)|hi16(b)<<16 in ONE v_perm_b32 (truncating bf16 pack)
__device__ __forceinline__ u32 pktrunc(float a, float b) {
    u32 ua = __float_as_uint(a), ub = __float_as_uint(b);
    return __builtin_amdgcn_perm(ub, ua, 0x07060302u);
}

// ---------------- kernel 1: per-block group partial sums (+ dtype flag), no atomics ------
__global__ void k_stats1(const void* x, float* gs2, int* flag) {
    int b = blockIdx.x, tid = threadIdx.x;          // 128 blocks, 32 rows each
    int lane = tid & 63, w = tid >> 6;
    __shared__ int cnt;
    __shared__ float red[4][32][2];
    if (tid == 0) cnt = 0;
    __syncthreads();
    const u16* u = (const u16*)x;
    int huge = 0;
    for (int i = tid; i < 1024; i += 256) {
        float a = fabsf(bf2f(u[i]));
        if (!(a < 1e4f)) huge++;
    }
    if (huge) atomicAdd(&cnt, huge);
    __syncthreads();
    int f32 = (cnt >= 8) ? 1 : 0;
    if (b == 0 && tid == 0) *flag = f32;
    float s1 = 0.f, s2 = 0.f;
    if (f32) {
        const float4* xp = (const float4*)x + b * 4096;
        #pragma unroll
        for (int i = 0; i < 16; i++) {
            float4 v = xp[i * 256 + tid];
            s1 += (v.x + v.y) + (v.z + v.w);
            s2 += (v.x*v.x + v.y*v.y) + (v.z*v.z + v.w*v.w);
        }
        s1 += __shfl_xor(s1, 1); s2 += __shfl_xor(s2, 1);
        s1 += __shfl_xor(s1, 2); s2 += __shfl_xor(s2, 2);
        if ((lane & 3) == 0) {
            int gl = (lane >> 2) + 16 * (w & 1);
            red[w][gl][0] = s1; red[w][gl][1] = s2;
        }
        __syncthreads();
        if (tid < 32) {
            int g = tid, w0 = (g < 16) ? 0 : 1;
            gs2[b * 64 + g * 2]     = red[w0][g][0] + red[w0 + 2][g][0];
            gs2[b * 64 + g * 2 + 1] = red[w0][g][1] + red[w0 + 2][g][1];
        }
    } else {
        const uint4* xp = (const uint4*)x + b * 2048;
        #pragma unroll
        for (int i = 0; i < 8; i++) {
            uint4 v = xp[i * 256 + tid];
            float f[8] = { bf2f((u16)(v.x&0xffff)), bf2f((u16)(v.x>>16)),
                           bf2f((u16)(v.y&0xffff)), bf2f((u16)(v.y>>16)),
                           bf2f((u16)(v.z&0xffff)), bf2f((u16)(v.z>>16)),
                           bf2f((u16)(v.w&0xffff)), bf2f((u16)(v.w>>16)) };
            #pragma unroll
            for (int j = 0; j < 8; j++) { s1 += f[j]; s2 += f[j]*f[j]; }
        }
        s1 += __shfl_xor(s1, 1); s2 += __shfl_xor(s2, 1);
        if ((lane & 1) == 0) { red[w][lane >> 1][0] = s1; red[w][lane >> 1][1] = s2; }
        __syncthreads();
        if (tid < 32) {
            int g = tid;
            gs2[b * 64 + g * 2]     = red[0][g][0]+red[1][g][0]+red[2][g][0]+red[3][g][0];
            gs2[b * 64 + g * 2 + 1] = red[0][g][1]+red[1][g][1]+red[2][g][1]+red[3][g][1];
        }
    }
}

// ---------------- kernel 2: fused normalize (blocks 0..1023) + weight transpose (1024..1279) --
__global__ void k_fuse(const void* x, const float* __restrict__ gs2,
                       const void* gsc, const void* gbi, const void* wq,
                       u16* __restrict__ xn, u16* __restrict__ wt,
                       const int* __restrict__ flag) {
    int bx = blockIdx.x, tid = threadIdx.x;
    int f32 = *flag;
    if (bx < 1024) {
        __shared__ float sred[64];
        if (tid < 64) {                              // reduce 128 block-partials (L2-hot)
            float a0 = 0.f, a1 = 0.f, a2 = 0.f, a3 = 0.f;
            const float* p = gs2 + tid;
            #pragma unroll
            for (int b = 0; b < 32; b++) {
                a0 += p[(4*b + 0) * 64];
                a1 += p[(4*b + 1) * 64];
                a2 += p[(4*b + 2) * 64];
                a3 += p[(4*b + 3) * 64];
            }
            sred[tid] = (a0 + a1) + (a2 + a3);
        }
        __syncthreads();
        int idx = (bx * 256 + tid) * 8;
        int c = idx & (C - 1);
        int g = c >> 4;
        float mean = sred[2 * g] * (1.0f / 65536.0f);
        float var  = sred[2 * g + 1] * (1.0f / 65536.0f) - mean * mean;
        float rstd = rsqrtf(var + EPS);
        float v[8];
        if (f32) {
            float4 x0 = *(const float4*)((const float*)x + idx);
            float4 x1 = *(const float4*)((const float*)x + idx + 4);
            v[0]=x0.x; v[1]=x0.y; v[2]=x0.z; v[3]=x0.w;
            v[4]=x1.x; v[5]=x1.y; v[6]=x1.z; v[7]=x1.w;
        } else {
            uint4 u = *(const uint4*)((const u16*)x + idx);
            v[0]=bf2f((u16)(u.x&0xffff)); v[1]=bf2f((u16)(u.x>>16));
            v[2]=bf2f((u16)(u.y&0xffff)); v[3]=bf2f((u16)(u.y>>16));
            v[4]=bf2f((u16)(u.z&0xffff)); v[5]=bf2f((u16)(u.z>>16));
            v[6]=bf2f((u16)(u.w&0xffff)); v[7]=bf2f((u16)(u.w>>16));
        }
        float r[8];
        #pragma unroll
        for (int i = 0; i < 8; i++) {
            float a = rstd * ldin(gsc, c + i, f32);
            r[i] = v[i] * a + (ldin(gbi, c + i, f32) - mean * a);
        }
        uint4 o;
        o.x = pk2bf(r[0], r[1]); o.y = pk2bf(r[2], r[3]);
        o.z = pk2bf(r[4], r[5]); o.w = pk2bf(r[6], r[7]);
        *(uint4*)(xn + idx) = o;
    } else {
        // transpose wq[k][col] -> wt[m][k], m = j*512+cc, col = 3*cc+j.
        __shared__ u16 Wl[48][64];
        int b = bx - 1024;                           // 0..255
        int k0 = (b >> 5) * 64, c0 = (b & 31) * 48;
        #pragma unroll
        for (int it = 0; it < 3; it++) {
            int u_ = it * 256 + tid;                 // 768 units = 64 rows x 12 col-quads
            int r = u_ / 12, cu = u_ % 12;
            int gi = (k0 + r) * 1536 + c0 + cu * 4;
            float v0, v1, v2, v3;
            if (f32) {
                float4 t4 = *(const float4*)((const float*)wq + gi);
                v0 = t4.x; v1 = t4.y; v2 = t4.z; v3 = t4.w;
            } else {
                uint2 t2 = *(const uint2*)((const u16*)wq + gi);
                v0 = bf2f((u16)(t2.x & 0xffff)); v1 = bf2f((u16)(t2.x >> 16));
                v2 = bf2f((u16)(t2.y & 0xffff)); v3 = bf2f((u16)(t2.y >> 16));
            }
            Wl[cu*4+0][r] = f2bf(v0); Wl[cu*4+1][r] = f2bf(v1);
            Wl[cu*4+2][r] = f2bf(v2); Wl[cu*4+3][r] = f2bf(v3);
        }
        __syncthreads();
        #pragma unroll
        for (int it = 0; it < 2; it++) {
            int u_ = it * 256 + tid;                 // 384 units = 48 m-rows x 8 k-chunks
            if (u_ < 384) {
                int mrow = u_ >> 3, kc = u_ & 7;
                int j = mrow >> 4, cci = mrow & 15;
                int m = j * 512 + (c0 / 3) + cci;
                int cl = 3 * cci + j;
                uint4 val = *(const uint4*)&Wl[cl][kc * 8];
                *(uint4*)(wt + m * 512 + k0 + kc * 8) = val;
            }
        }
    }
}

// ---------------- kernel 3: QKV GEMM, 64x128 tiles, BK=64, double-buffered ----------------
// V epilogue stores vt with key-index bits 2<->3 swapped (sigma) so k_attn's PV B-operand
// is the lane's own S registers (no cross-lane exchange).
__global__ __launch_bounds__(256) void k_gemm(
    const u16* __restrict__ xn, const u16* __restrict__ wt,
    const void* __restrict__ bq, const int* __restrict__ flag,
    u16* __restrict__ qh, u16* __restrict__ kh, u16* __restrict__ vt)
{
    __shared__ char smem[49152];
    u16* Al = (u16*)smem;                        // 2 x 8KB
    u16* Bl = (u16*)(smem + 16384);              // 2 x 16KB
    int bx = blockIdx.x;
    int bm = bx & 63, bn = bx >> 6;              // 64 x 12
    int tid = threadIdx.x;
    int w = tid >> 6, lane = tid & 63, quad = lane >> 4, l15 = lane & 15;
    f32x4 acc[4][2] = {};
    const u16* Ag = xn + bm * 64 * 512;
    const u16* Bg = wt + bn * 128 * 512;

    #pragma unroll
    for (int i = 0; i < 2; i++) {
        int L = i * 256 + tid, row = L >> 3, cc = ((L & 7) ^ (row & 7)) * 8;
        async16(Ag + row * 512 + cc, (void*)(Al + L * 8));
    }
    #pragma unroll
    for (int i = 0; i < 4; i++) {
        int L = i * 256 + tid, row = L >> 3, cc = ((L & 7) ^ (row & 7)) * 8;
        async16(Bg + row * 512 + cc, (void*)(Bl + L * 8));
    }

    #pragma unroll
    for (int ki = 0; ki < 8; ki++) {
        __syncthreads();
        if (ki < 7) {
            int kn = (ki + 1) * 64;
            int bo = ((ki + 1) & 1);
            #pragma unroll
            for (int i = 0; i < 2; i++) {
                int L = i * 256 + tid, row = L >> 3, cc = ((L & 7) ^ (row & 7)) * 8;
                async16(Ag + row * 512 + kn + cc, (void*)(Al + bo * 4096 + L * 8));
            }
            #pragma unroll
            for (int i = 0; i < 4; i++) {
                int L = i * 256 + tid, row = L >> 3, cc = ((L & 7) ^ (row & 7)) * 8;
                async16(Bg + row * 512 + kn + cc, (void*)(Bl + bo * 8192 + L * 8));
            }
        }
        const u16* Ab = Al + (ki & 1) * 4096;
        const u16* Bb = Bl + (ki & 1) * 8192;
        #pragma unroll
        for (int kk = 0; kk < 2; kk++) {
            bf16x8 af[4], bfr[2];
            #pragma unroll
            for (int mi = 0; mi < 4; mi++) {
                int row = mi * 16 + l15;
                af[mi] = *(const bf16x8*)(Ab + row * 64 + (((kk * 4 + quad) ^ (row & 7)) * 8));
            }
            #pragma unroll
            for (int ni = 0; ni < 2; ni++) {
                int row = w * 32 + ni * 16 + l15;
                bfr[ni] = *(const bf16x8*)(Bb + row * 64 + (((kk * 4 + quad) ^ (row & 7)) * 8));
            }
            #pragma unroll
            for (int mi = 0; mi < 4; mi++)
                #pragma unroll
                for (int ni = 0; ni < 2; ni++)
                    acc[mi][ni] = __builtin_amdgcn_mfma_f32_16x16x32_bf16(
                        af[mi], bfr[ni], acc[mi][ni], 0, 0, 0);
        }
    }
    int f32 = *flag;
    int t_base = bm * 64;
    int j = bn >> 2;                              // uniform per block
    if (j < 2) {
        u16* dst = j ? kh : qh;
        float s = j ? QKS : QKS_Q;
        #pragma unroll
        for (int ni = 0; ni < 2; ni++) {
            int n = bn * 128 + w * 32 + ni * 16 + l15;
            int r = n & 511, hh = r >> 6, cc = r & 63;
            float bias = ldin(bq, 3 * r + j, f32);
            #pragma unroll
            for (int mi = 0; mi < 4; mi++) {
                int tq = t_base + mi * 16 + quad * 4;
                #pragma unroll
                for (int rg = 0; rg < 4; rg++)
                    dst[(hh * T + tq + rg) * CH + cc] = f2bf((acc[mi][ni][rg] + bias) * s);
            }
        }
    } else {
        __syncthreads();
        u16* Tt = (u16*)smem;
        u16* Tw = Tt + w * 2048;
        int rbase = (bn - 8) * 128 + w * 32;
        int hh = rbase >> 6;                      // uniform per wave
        #pragma unroll
        for (int ni = 0; ni < 2; ni++) {
            int r = rbase + ni * 16 + l15;
            float bias = ldin(bq, 3 * (r & 511) + 2, f32);
            int rl = ni * 16 + l15;
            #pragma unroll
            for (int mi = 0; mi < 4; mi++) {
                uint2 pv;
                pv.x = pk2bf(acc[mi][ni][0] + bias, acc[mi][ni][1] + bias);
                pv.y = pk2bf(acc[mi][ni][2] + bias, acc[mi][ni][3] + bias);
                int cs = (mi * 2 + (quad >> 1)) ^ (rl & 7);
                *(uint2*)((u32*)Tw + rl * 32 + cs * 4 + (quad & 1) * 2) = pv;
            }
        }
        // sigma-permuted store: key-index bits 2<->3 swapped so PV B-frags in k_attn are
        // the lane's own S registers.
        int cc_hi = (w & 1) * 32;
        #pragma unroll
        for (int rr = 0; rr < 4; rr++) {
            int rl = rr * 8 + (lane >> 3);
            int g = lane & 7;
            int cA = (g & ~1) ^ (rl & 7);
            int cB = ((g & ~1) + 1) ^ (rl & 7);
            int ofs = (g & 1) * 4;
            uint2 a = *(const uint2*)(Tw + rl * 64 + cA * 8 + ofs);
            uint2 b = *(const uint2*)(Tw + rl * 64 + cB * 8 + ofs);
            *(uint4*)(vt + (hh * CH + cc_hi + rl) * T + t_base + g * 8) =
                make_uint4(a.x, a.y, b.x, b.y);
        }
    }
}

// ---------------- kernel 4: flash attention v9 ----------
// grid 1024 = (h, qb, ks): 128 q x 1024 keys; single barrier/iter; K+V dbuf.
// S^T 32x32x16 -> P B-frags are the lane's OWN packed S regs (vt key-permuted).
// Partials to workspace; separate k_fin merges (cross-XCD visibility via dispatch
// boundary — device-scope fences in-kernel cost ~2x the whole kernel, r8).
__global__ __launch_bounds__(256, 4) void k_attn(
    const u16* __restrict__ qh, const u16* __restrict__ kh,
    const u16* __restrict__ vt, float* __restrict__ opart, float* __restrict__ ls)
{
    __shared__ char lds[32768];
    u16* K0 = (u16*)lds;                         // 2 x 8KB K dbuf
    u16* V0 = (u16*)(lds + 16384);               // 2 x 8KB V dbuf
    int bx = blockIdx.x;
    int h = bx >> 7, qb = (bx >> 2) & 31, ks = bx & 3;
    int t0 = qb * 128;
    int tid = threadIdx.x;
    int w = tid >> 6, lane = tid & 63;
    int l31 = lane & 31, hi = lane >> 5;

    const u16* Kg = kh + (h * T + ks * 1024) * CH;
    const u16* Vg = vt + h * CH * T + ks * 1024;

    int L0 = tid,       r0 = L0 >> 3, c0 = ((L0 & 7) ^ (r0 & 7)) * 8;
    int L1 = 256 + tid, r1 = L1 >> 3, c1 = ((L1 & 7) ^ (r1 & 7)) * 8;
    const u16* kp0 = Kg + r0 * CH + c0;
    const u16* kp1 = Kg + r1 * CH + c1;
    const u16* vp0 = Vg + r0 * T + c0;
    const u16* vp1 = Vg + r1 * T + c1;

    int off[2][4];
    #pragma unroll
    for (int rt = 0; rt < 2; rt++)
        #pragma unroll
        for (int c = 0; c < 4; c++) {
            int row = rt * 32 + l31;
            off[rt][c] = row * 64 + (((2 * c + hi) ^ (row & 7)) * 8);
        }

    bf16x8 bq[4];
    {
        const u16* qrow = qh + (h * T + t0 + w * 32 + l31) * CH;
        #pragma unroll
        for (int ksi = 0; ksi < 4; ksi++)
            bq[ksi] = *(const bf16x8*)(qrow + ksi * 16 + hi * 8);
    }

    async16(kp0, (void*)(K0 + L0 * 8));
    async16(kp1, (void*)(K0 + L1 * 8));
    async16(vp0, (void*)(V0 + L0 * 8));
    async16(vp1, (void*)(V0 + L1 * 8));

    f32x16 o[2] = {};
    float lsum = 0.f;

    for (int kt = 0; kt < 16; kt++) {
        int par = (kt & 1) * 4096;
        const u16* Kc = K0 + par;
        const u16* Vc = V0 + par;
        __syncthreads();                         // tile kt staged & visible; kt-1 reads done
        if (kt < 15) {                           // prefetch kt+1, drains at NEXT barrier
            int nx = ((kt + 1) & 1) * 4096;
            int ko = (kt + 1) * 64 * CH;
            int vo = (kt + 1) * 64;
            async16(kp0 + ko, (void*)(K0 + nx + L0 * 8));
            async16(kp1 + ko, (void*)(K0 + nx + L1 * 8));
            async16(vp0 + vo, (void*)(V0 + nx + L0 * 8));
            async16(vp1 + vo, (void*)(V0 + nx + L1 * 8));
        }
        // S^T = K . Q^T -> D[key][q]
        f32x16 sa[2] = {};
        #pragma unroll
        for (int t = 0; t < 2; t++)
            #pragma unroll
            for (int ksi = 0; ksi < 4; ksi++) {
                bf16x8 aK = *(const bf16x8*)(Kc + off[t][ksi]);
                sa[t] = __builtin_amdgcn_mfma_f32_32x32x16_bf16(aK, bq[ksi], sa[t], 0, 0, 0);
            }
        // softmax (exp2 domain) + DIRECT B-frag pack (vt is sigma-permuted: no exchange)
        u32 bp[4][4];
        #pragma unroll
        for (int t = 0; t < 2; t++) {
            float rs = 0.f;
            #pragma unroll
            for (int pi = 0; pi < 8; pi++) {
                float e0 = exp2f(sa[t][2 * pi]);
                float e1 = exp2f(sa[t][2 * pi + 1]);
                rs += e0 + e1;
                bp[2 * t + (pi >> 2)][pi & 3] = pktrunc(e0, e1);
            }
            lsum += rs;
        }
        // O^T += V^T . P -> D[d][q]
        #pragma unroll
        for (int dt = 0; dt < 2; dt++)
            #pragma unroll
            for (int kst = 0; kst < 4; kst++) {
                bf16x8 aV = *(const bf16x8*)(Vc + off[dt][kst]);
                bf16x8 bpv;
                __builtin_memcpy(&bpv, bp[kst], 16);
                o[dt] = __builtin_amdgcn_mfma_f32_32x32x16_bf16(aV, bpv, o[dt], 0, 0, 0);
            }
    }
    lsum += __shfl_xor(lsum, 32);                // merge key-halves (same q)

    __syncthreads();                             // all waves done with K/V LDS
    float* Sw = (float*)(lds + w * 6144);        // per-wave strip: [32 q][33] fp32
    int qg = t0 + w * 32;
    int q2 = lane >> 1, half = lane & 1;
    #pragma unroll
    for (int dt = 0; dt < 2; dt++) {
        #pragma unroll
        for (int reg = 0; reg < 16; reg++) {
            int dl = (reg & 3) + 8 * (reg >> 2) + 4 * hi;
            Sw[l31 * 33 + dl] = o[dt][reg];
        }
        const float* src = Sw + q2 * 33 + half * 16;
        float* dst = opart + ((ks * 8 + h) * T + qg + q2) * 64 + dt * 32 + half * 16;
        #pragma unroll
        for (int i = 0; i < 4; i++)
            *(f32x4*)(dst + i * 4) = *(const f32x4*)(src + i * 4);
    }
    if (hi == 0) ls[(ks * 8 + h) * T + qg + l31] = lsum;
}

// ---------------- kernel 5: merge 4 key-split partials, normalize, store out ----------------
__global__ void k_fin(const float* __restrict__ opart, const float* __restrict__ ls,
                      void* __restrict__ out, const int* __restrict__ flag) {
    int idx = (blockIdx.x * 256 + threadIdx.x) * 8;   // over [h][t][d] = 2M, grid 1024
    int d0 = idx & 63;
    int ht = idx >> 6;
    int t = ht & (T - 1), h = ht >> 12;
    float inv = 1.0f / (ls[ht] + ls[32768 + ht] + ls[65536 + ht] + ls[98304 + ht]);
    float v[8] = {};
    #pragma unroll
    for (int ks = 0; ks < 4; ks++) {
        float4 a0 = *(const float4*)(opart + ks * 2097152 + idx);
        float4 a1 = *(const float4*)(opart + ks * 2097152 + idx + 4);
        v[0] += a0.x; v[1] += a0.y; v[2] += a0.z; v[3] += a0.w;
        v[4] += a1.x; v[5] += a1.y; v[6] += a1.z; v[7] += a1.w;
    }
    #pragma unroll
    for (int i = 0; i < 8; i++) v[i] *= inv;
    int gbase = t * C + h * CH + d0;
    if (*flag) {
        *(float4*)((float*)out + gbase)     = make_float4(v[0], v[1], v[2], v[3]);
        *(float4*)((float*)out + gbase + 4) = make_float4(v[4], v[5], v[6], v[7]);
    } else {
        uint4 o;
        o.x = pk2bf(v[0], v[1]); o.y = pk2bf(v[2], v[3]);
        o.z = pk2bf(v[4], v[5]); o.w = pk2bf(v[6], v[7]);
        *(uint4*)((u16*)out + gbase) = o;
    }
}

extern "C" void kernel_launch(void* const* d_in, const int* in_sizes, int n_in,
                              void* d_out, int out_size, void* d_ws, size_t ws_size,
                              hipStream_t stream) {
    const void* x   = d_in[0];
    const void* gsc = d_in[1];
    const void* gbi = d_in[2];
    const void* wq  = d_in[3];
    const void* bq  = d_in[4];
    char* ws = (char*)d_ws;
    int*   flag = (int*)ws;                          // 4 B
    char* base = ws + 8192;
    u16* qh = (u16*)(base);                          // 4 MB
    u16* kh = (u16*)(base + 4194304);                // 4 MB
    u16* vt = (u16*)(base + 8388608);                // 4 MB (sigma key-permuted)
    u16* xn = (u16*)(base + 12582912);               // 4 MB   (dead after k_gemm)
    u16* wt = (u16*)(base + 16777216);               // 1.5 MB (dead after k_gemm)
    float* opart = (float*)(base + 12582912);        // 32 MB, overlaps xn/wt
    float* ls    = (float*)(base + 46137344);        // 512 KB
    float* gs2   = (float*)(base + 46661632);        // 32 KB per-block group partials

    hipLaunchKernelGGL(k_stats1, dim3(128),  dim3(256), 0, stream, x, gs2, flag);
    hipLaunchKernelGGL(k_fuse,   dim3(1280), dim3(256), 0, stream, x, gs2, gsc, gbi, wq, xn, wt, flag);
    hipLaunchKernelGGL(k_gemm,   dim3(768),  dim3(256), 0, stream, xn, wt, bq, flag, qh, kh, vt);
    hipLaunchKernelGGL(k_attn,   dim3(1024), dim3(256), 0, stream, qh, kh, vt, opart, ls);
    hipLaunchKernelGGL(k_fin,    dim3(1024), dim3(256), 0, stream, opart, ls, d_out, flag);
}

// Round 10
// 157.189 us; speedup vs baseline: 2.5819x; 1.0183x over previous
//
#include <hip/hip_runtime.h>
#include <hip/hip_bf16.h>
#include <stdint.h>

typedef __attribute__((ext_vector_type(8))) short bf16x8;
typedef __attribute__((ext_vector_type(4))) float f32x4;
typedef __attribute__((ext_vector_type(16))) float f32x16;
typedef unsigned short u16;
typedef unsigned int u32;

constexpr int T  = 4096;
constexpr int C  = 512;
constexpr int H  = 8;
constexpr int CH = 64;
constexpr float EPS = 1e-6f;
constexpr float QKS   = 0.35355339059327378f;                       // 64^-0.25
constexpr float QKS_Q = 0.35355339059327378f * 1.4426950408889634f; // fold log2e into q

__device__ __forceinline__ float bf2f(u16 u) {
    union { unsigned int i; float f; } v; v.i = ((unsigned int)u) << 16; return v.f;
}
__device__ __forceinline__ u16 f2bf(float f) {
    union { float f; unsigned int i; } v; v.f = f;
    return (u16)((v.i + 0x7FFFu + ((v.i >> 16) & 1u)) >> 16);
}
__device__ __forceinline__ u32 pk2bf(float a, float b) {
    __hip_bfloat162 h = __float22bfloat162_rn(make_float2(a, b));
    u32 r; __builtin_memcpy(&r, &h, 4); return r;
}
__device__ __forceinline__ float ldin(const void* p, int i, int f32) {
    return f32 ? ((const float*)p)[i] : bf2f(((const u16*)p)[i]);
}
__device__ __forceinline__ void async16(const void* g, void* l) {
    __builtin_amdgcn_global_load_lds(
        (const __attribute__((address_space(1))) void*)g,
        (__attribute__((address_space(3))) void*)l,
        16, 0, 0);
}
// pack hi16(a)|hi16(b)<<16 in ONE v_perm_b32 (truncating bf16 pack)
__device__ __forceinline__ u32 pktrunc(float a, float b) {
    u32 ua = __float_as_uint(a), ub = __float_as_uint(b);
    return __builtin_amdgcn_perm(ub, ua, 0x07060302u);
}

// ---------------- kernel 1: per-block group partial sums (+ dtype flag), no atomics ------
__global__ void k_stats1(const void* x, float* gs2, int* flag) {
    int b = blockIdx.x, tid = threadIdx.x;          // 128 blocks, 32 rows each
    int lane = tid & 63, w = tid >> 6;
    __shared__ int cnt;
    __shared__ float red[4][32][2];
    if (tid == 0) cnt = 0;
    __syncthreads();
    const u16* u = (const u16*)x;
    int huge = 0;
    for (int i = tid; i < 1024; i += 256) {
        float a = fabsf(bf2f(u[i]));
        if (!(a < 1e4f)) huge++;
    }
    if (huge) atomicAdd(&cnt, huge);
    __syncthreads();
    int f32 = (cnt >= 8) ? 1 : 0;
    if (b == 0 && tid == 0) *flag = f32;
    float s1 = 0.f, s2 = 0.f;
    if (f32) {
        const float4* xp = (const float4*)x + b * 4096;
        #pragma unroll
        for (int i = 0; i < 16; i++) {
            float4 v = xp[i * 256 + tid];
            s1 += (v.x + v.y) + (v.z + v.w);
            s2 += (v.x*v.x + v.y*v.y) + (v.z*v.z + v.w*v.w);
        }
        s1 += __shfl_xor(s1, 1); s2 += __shfl_xor(s2, 1);
        s1 += __shfl_xor(s1, 2); s2 += __shfl_xor(s2, 2);
        if ((lane & 3) == 0) {
            int gl = (lane >> 2) + 16 * (w & 1);
            red[w][gl][0] = s1; red[w][gl][1] = s2;
        }
        __syncthreads();
        if (tid < 32) {
            int g = tid, w0 = (g < 16) ? 0 : 1;
            gs2[b * 64 + g * 2]     = red[w0][g][0] + red[w0 + 2][g][0];
            gs2[b * 64 + g * 2 + 1] = red[w0][g][1] + red[w0 + 2][g][1];
        }
    } else {
        const uint4* xp = (const uint4*)x + b * 2048;
        #pragma unroll
        for (int i = 0; i < 8; i++) {
            uint4 v = xp[i * 256 + tid];
            float f[8] = { bf2f((u16)(v.x&0xffff)), bf2f((u16)(v.x>>16)),
                           bf2f((u16)(v.y&0xffff)), bf2f((u16)(v.y>>16)),
                           bf2f((u16)(v.z&0xffff)), bf2f((u16)(v.z>>16)),
                           bf2f((u16)(v.w&0xffff)), bf2f((u16)(v.w>>16)) };
            #pragma unroll
            for (int j = 0; j < 8; j++) { s1 += f[j]; s2 += f[j]*f[j]; }
        }
        s1 += __shfl_xor(s1, 1); s2 += __shfl_xor(s2, 1);
        if ((lane & 1) == 0) { red[w][lane >> 1][0] = s1; red[w][lane >> 1][1] = s2; }
        __syncthreads();
        if (tid < 32) {
            int g = tid;
            gs2[b * 64 + g * 2]     = red[0][g][0]+red[1][g][0]+red[2][g][0]+red[3][g][0];
            gs2[b * 64 + g * 2 + 1] = red[0][g][1]+red[1][g][1]+red[2][g][1]+red[3][g][1];
        }
    }
}

// ---------------- kernel 2: fused normalize (blocks 0..1023) + weight transpose (1024..1279) --
__global__ void k_fuse(const void* x, const float* __restrict__ gs2,
                       const void* gsc, const void* gbi, const void* wq,
                       u16* __restrict__ xn, u16* __restrict__ wt,
                       const int* __restrict__ flag) {
    int bx = blockIdx.x, tid = threadIdx.x;
    int f32 = *flag;
    if (bx < 1024) {
        __shared__ float sred[64];
        if (tid < 64) {                              // reduce 128 block-partials (L2-hot)
            float a0 = 0.f, a1 = 0.f, a2 = 0.f, a3 = 0.f;
            const float* p = gs2 + tid;
            #pragma unroll
            for (int b = 0; b < 32; b++) {
                a0 += p[(4*b + 0) * 64];
                a1 += p[(4*b + 1) * 64];
                a2 += p[(4*b + 2) * 64];
                a3 += p[(4*b + 3) * 64];
            }
            sred[tid] = (a0 + a1) + (a2 + a3);
        }
        __syncthreads();
        int idx = (bx * 256 + tid) * 8;
        int c = idx & (C - 1);
        int g = c >> 4;
        float mean = sred[2 * g] * (1.0f / 65536.0f);
        float var  = sred[2 * g + 1] * (1.0f / 65536.0f) - mean * mean;
        float rstd = rsqrtf(var + EPS);
        float v[8];
        if (f32) {
            float4 x0 = *(const float4*)((const float*)x + idx);
            float4 x1 = *(const float4*)((const float*)x + idx + 4);
            v[0]=x0.x; v[1]=x0.y; v[2]=x0.z; v[3]=x0.w;
            v[4]=x1.x; v[5]=x1.y; v[6]=x1.z; v[7]=x1.w;
        } else {
            uint4 u = *(const uint4*)((const u16*)x + idx);
            v[0]=bf2f((u16)(u.x&0xffff)); v[1]=bf2f((u16)(u.x>>16));
            v[2]=bf2f((u16)(u.y&0xffff)); v[3]=bf2f((u16)(u.y>>16));
            v[4]=bf2f((u16)(u.z&0xffff)); v[5]=bf2f((u16)(u.z>>16));
            v[6]=bf2f((u16)(u.w&0xffff)); v[7]=bf2f((u16)(u.w>>16));
        }
        float r[8];
        #pragma unroll
        for (int i = 0; i < 8; i++) {
            float a = rstd * ldin(gsc, c + i, f32);
            r[i] = v[i] * a + (ldin(gbi, c + i, f32) - mean * a);
        }
        uint4 o;
        o.x = pk2bf(r[0], r[1]); o.y = pk2bf(r[2], r[3]);
        o.z = pk2bf(r[4], r[5]); o.w = pk2bf(r[6], r[7]);
        *(uint4*)(xn + idx) = o;
    } else {
        // transpose wq[k][col] -> wt[m][k], m = j*512+cc, col = 3*cc+j.
        __shared__ u16 Wl[48][64];
        int b = bx - 1024;                           // 0..255
        int k0 = (b >> 5) * 64, c0 = (b & 31) * 48;
        #pragma unroll
        for (int it = 0; it < 3; it++) {
            int u_ = it * 256 + tid;                 // 768 units = 64 rows x 12 col-quads
            int r = u_ / 12, cu = u_ % 12;
            int gi = (k0 + r) * 1536 + c0 + cu * 4;
            float v0, v1, v2, v3;
            if (f32) {
                float4 t4 = *(const float4*)((const float*)wq + gi);
                v0 = t4.x; v1 = t4.y; v2 = t4.z; v3 = t4.w;
            } else {
                uint2 t2 = *(const uint2*)((const u16*)wq + gi);
                v0 = bf2f((u16)(t2.x & 0xffff)); v1 = bf2f((u16)(t2.x >> 16));
                v2 = bf2f((u16)(t2.y & 0xffff)); v3 = bf2f((u16)(t2.y >> 16));
            }
            Wl[cu*4+0][r] = f2bf(v0); Wl[cu*4+1][r] = f2bf(v1);
            Wl[cu*4+2][r] = f2bf(v2); Wl[cu*4+3][r] = f2bf(v3);
        }
        __syncthreads();
        #pragma unroll
        for (int it = 0; it < 2; it++) {
            int u_ = it * 256 + tid;                 // 384 units = 48 m-rows x 8 k-chunks
            if (u_ < 384) {
                int mrow = u_ >> 3, kc = u_ & 7;
                int j = mrow >> 4, cci = mrow & 15;
                int m = j * 512 + (c0 / 3) + cci;
                int cl = 3 * cci + j;
                uint4 val = *(const uint4*)&Wl[cl][kc * 8];
                *(uint4*)(wt + m * 512 + k0 + kc * 8) = val;
            }
        }
    }
}

// ---------------- kernel 3: QKV GEMM, 64x128 tiles, BK=64, double-buffered ----------------
// V epilogue stores vt with key-index bits 2<->3 swapped (sigma) so k_attn's PV B-operand
// is the lane's own S registers (no cross-lane exchange).
__global__ __launch_bounds__(256) void k_gemm(
    const u16* __restrict__ xn, const u16* __restrict__ wt,
    const void* __restrict__ bq, const int* __restrict__ flag,
    u16* __restrict__ qh, u16* __restrict__ kh, u16* __restrict__ vt)
{
    __shared__ char smem[49152];
    u16* Al = (u16*)smem;                        // 2 x 8KB
    u16* Bl = (u16*)(smem + 16384);              // 2 x 16KB
    int bx = blockIdx.x;
    int bm = bx & 63, bn = bx >> 6;              // 64 x 12
    int tid = threadIdx.x;
    int w = tid >> 6, lane = tid & 63, quad = lane >> 4, l15 = lane & 15;
    f32x4 acc[4][2] = {};
    const u16* Ag = xn + bm * 64 * 512;
    const u16* Bg = wt + bn * 128 * 512;

    #pragma unroll
    for (int i = 0; i < 2; i++) {
        int L = i * 256 + tid, row = L >> 3, cc = ((L & 7) ^ (row & 7)) * 8;
        async16(Ag + row * 512 + cc, (void*)(Al + L * 8));
    }
    #pragma unroll
    for (int i = 0; i < 4; i++) {
        int L = i * 256 + tid, row = L >> 3, cc = ((L & 7) ^ (row & 7)) * 8;
        async16(Bg + row * 512 + cc, (void*)(Bl + L * 8));
    }

    #pragma unroll
    for (int ki = 0; ki < 8; ki++) {
        __syncthreads();
        if (ki < 7) {
            int kn = (ki + 1) * 64;
            int bo = ((ki + 1) & 1);
            #pragma unroll
            for (int i = 0; i < 2; i++) {
                int L = i * 256 + tid, row = L >> 3, cc = ((L & 7) ^ (row & 7)) * 8;
                async16(Ag + row * 512 + kn + cc, (void*)(Al + bo * 4096 + L * 8));
            }
            #pragma unroll
            for (int i = 0; i < 4; i++) {
                int L = i * 256 + tid, row = L >> 3, cc = ((L & 7) ^ (row & 7)) * 8;
                async16(Bg + row * 512 + kn + cc, (void*)(Bl + bo * 8192 + L * 8));
            }
        }
        const u16* Ab = Al + (ki & 1) * 4096;
        const u16* Bb = Bl + (ki & 1) * 8192;
        #pragma unroll
        for (int kk = 0; kk < 2; kk++) {
            bf16x8 af[4], bfr[2];
            #pragma unroll
            for (int mi = 0; mi < 4; mi++) {
                int row = mi * 16 + l15;
                af[mi] = *(const bf16x8*)(Ab + row * 64 + (((kk * 4 + quad) ^ (row & 7)) * 8));
            }
            #pragma unroll
            for (int ni = 0; ni < 2; ni++) {
                int row = w * 32 + ni * 16 + l15;
                bfr[ni] = *(const bf16x8*)(Bb + row * 64 + (((kk * 4 + quad) ^ (row & 7)) * 8));
            }
            #pragma unroll
            for (int mi = 0; mi < 4; mi++)
                #pragma unroll
                for (int ni = 0; ni < 2; ni++)
                    acc[mi][ni] = __builtin_amdgcn_mfma_f32_16x16x32_bf16(
                        af[mi], bfr[ni], acc[mi][ni], 0, 0, 0);
        }
    }
    int f32 = *flag;
    int t_base = bm * 64;
    int j = bn >> 2;                              // uniform per block
    if (j < 2) {
        u16* dst = j ? kh : qh;
        float s = j ? QKS : QKS_Q;
        #pragma unroll
        for (int ni = 0; ni < 2; ni++) {
            int n = bn * 128 + w * 32 + ni * 16 + l15;
            int r = n & 511, hh = r >> 6, cc = r & 63;
            float bias = ldin(bq, 3 * r + j, f32);
            #pragma unroll
            for (int mi = 0; mi < 4; mi++) {
                int tq = t_base + mi * 16 + quad * 4;
                #pragma unroll
                for (int rg = 0; rg < 4; rg++)
                    dst[(hh * T + tq + rg) * CH + cc] = f2bf((acc[mi][ni][rg] + bias) * s);
            }
        }
    } else {
        __syncthreads();
        u16* Tt = (u16*)smem;
        u16* Tw = Tt + w * 2048;
        int rbase = (bn - 8) * 128 + w * 32;
        int hh = rbase >> 6;                      // uniform per wave
        #pragma unroll
        for (int ni = 0; ni < 2; ni++) {
            int r = rbase + ni * 16 + l15;
            float bias = ldin(bq, 3 * (r & 511) + 2, f32);
            int rl = ni * 16 + l15;
            #pragma unroll
            for (int mi = 0; mi < 4; mi++) {
                uint2 pv;
                pv.x = pk2bf(acc[mi][ni][0] + bias, acc[mi][ni][1] + bias);
                pv.y = pk2bf(acc[mi][ni][2] + bias, acc[mi][ni][3] + bias);
                int cs = (mi * 2 + (quad >> 1)) ^ (rl & 7);
                *(uint2*)((u32*)Tw + rl * 32 + cs * 4 + (quad & 1) * 2) = pv;
            }
        }
        // sigma-permuted store: key-index bits 2<->3 swapped so PV B-frags in k_attn are
        // the lane's own S registers.
        int cc_hi = (w & 1) * 32;
        #pragma unroll
        for (int rr = 0; rr < 4; rr++) {
            int rl = rr * 8 + (lane >> 3);
            int g = lane & 7;
            int cA = (g & ~1) ^ (rl & 7);
            int cB = ((g & ~1) + 1) ^ (rl & 7);
            int ofs = (g & 1) * 4;
            uint2 a = *(const uint2*)(Tw + rl * 64 + cA * 8 + ofs);
            uint2 b = *(const uint2*)(Tw + rl * 64 + cB * 8 + ofs);
            *(uint4*)(vt + (hh * CH + cc_hi + rl) * T + t_base + g * 8) =
                make_uint4(a.x, a.y, b.x, b.y);
        }
    }
}

// ---------------- kernel 4: flash attention v10 ----------
// grid 2048 = (h, qb, ks=8): 128 q x 512 keys; single barrier/iter; K+V dbuf (32KB).
// Runtime occupancy LDS-capped at 5 blocks/CU (20 waves). bf16 partials to workspace.
__global__ __launch_bounds__(256, 4) void k_attn(
    const u16* __restrict__ qh, const u16* __restrict__ kh,
    const u16* __restrict__ vt, u16* __restrict__ opart, float* __restrict__ ls)
{
    __shared__ char lds[32768];
    u16* K0 = (u16*)lds;                         // 2 x 8KB K dbuf
    u16* V0 = (u16*)(lds + 16384);               // 2 x 8KB V dbuf
    int bx = blockIdx.x;
    int h = bx >> 8, qb = (bx >> 3) & 31, ks = bx & 7;
    int t0 = qb * 128;
    int tid = threadIdx.x;
    int w = tid >> 6, lane = tid & 63;
    int l31 = lane & 31, hi = lane >> 5;

    const u16* Kg = kh + (h * T + ks * 512) * CH;
    const u16* Vg = vt + h * CH * T + ks * 512;

    int L0 = tid,       r0 = L0 >> 3, c0 = ((L0 & 7) ^ (r0 & 7)) * 8;
    int L1 = 256 + tid, r1 = L1 >> 3, c1 = ((L1 & 7) ^ (r1 & 7)) * 8;
    const u16* kp0 = Kg + r0 * CH + c0;
    const u16* kp1 = Kg + r1 * CH + c1;
    const u16* vp0 = Vg + r0 * T + c0;
    const u16* vp1 = Vg + r1 * T + c1;

    int off[2][4];
    #pragma unroll
    for (int rt = 0; rt < 2; rt++)
        #pragma unroll
        for (int c = 0; c < 4; c++) {
            int row = rt * 32 + l31;
            off[rt][c] = row * 64 + (((2 * c + hi) ^ (row & 7)) * 8);
        }

    bf16x8 bq[4];
    {
        const u16* qrow = qh + (h * T + t0 + w * 32 + l31) * CH;
        #pragma unroll
        for (int ksi = 0; ksi < 4; ksi++)
            bq[ksi] = *(const bf16x8*)(qrow + ksi * 16 + hi * 8);
    }

    async16(kp0, (void*)(K0 + L0 * 8));
    async16(kp1, (void*)(K0 + L1 * 8));
    async16(vp0, (void*)(V0 + L0 * 8));
    async16(vp1, (void*)(V0 + L1 * 8));

    f32x16 o[2] = {};
    float lsum = 0.f;

    for (int kt = 0; kt < 8; kt++) {
        int par = (kt & 1) * 4096;
        const u16* Kc = K0 + par;
        const u16* Vc = V0 + par;
        __syncthreads();                         // tile kt staged & visible; kt-1 reads done
        if (kt < 7) {                            // prefetch kt+1, drains at NEXT barrier
            int nx = ((kt + 1) & 1) * 4096;
            int ko = (kt + 1) * 64 * CH;
            int vo = (kt + 1) * 64;
            async16(kp0 + ko, (void*)(K0 + nx + L0 * 8));
            async16(kp1 + ko, (void*)(K0 + nx + L1 * 8));
            async16(vp0 + vo, (void*)(V0 + nx + L0 * 8));
            async16(vp1 + vo, (void*)(V0 + nx + L1 * 8));
        }
        // S^T = K . Q^T -> D[key][q]
        f32x16 sa[2] = {};
        #pragma unroll
        for (int t = 0; t < 2; t++)
            #pragma unroll
            for (int ksi = 0; ksi < 4; ksi++) {
                bf16x8 aK = *(const bf16x8*)(Kc + off[t][ksi]);
                sa[t] = __builtin_amdgcn_mfma_f32_32x32x16_bf16(aK, bq[ksi], sa[t], 0, 0, 0);
            }
        // softmax (exp2 domain) + DIRECT B-frag pack (vt is sigma-permuted: no exchange)
        u32 bp[4][4];
        #pragma unroll
        for (int t = 0; t < 2; t++) {
            float rs = 0.f;
            #pragma unroll
            for (int pi = 0; pi < 8; pi++) {
                float e0 = exp2f(sa[t][2 * pi]);
                float e1 = exp2f(sa[t][2 * pi + 1]);
                rs += e0 + e1;
                bp[2 * t + (pi >> 2)][pi & 3] = pktrunc(e0, e1);
            }
            lsum += rs;
        }
        // O^T += V^T . P -> D[d][q]
        #pragma unroll
        for (int dt = 0; dt < 2; dt++)
            #pragma unroll
            for (int kst = 0; kst < 4; kst++) {
                bf16x8 aV = *(const bf16x8*)(Vc + off[dt][kst]);
                bf16x8 bpv;
                __builtin_memcpy(&bpv, bp[kst], 16);
                o[dt] = __builtin_amdgcn_mfma_f32_32x32x16_bf16(aV, bpv, o[dt], 0, 0, 0);
            }
    }
    lsum += __shfl_xor(lsum, 32);                // merge key-halves (same q)

    __syncthreads();                             // all waves done with K/V LDS
    float* Sw = (float*)(lds + w * 6144);        // per-wave strip: [32 q][33] fp32
    int qg = t0 + w * 32;
    int q2 = lane >> 1, half = lane & 1;
    #pragma unroll
    for (int dt = 0; dt < 2; dt++) {
        #pragma unroll
        for (int reg = 0; reg < 16; reg++) {
            int dl = (reg & 3) + 8 * (reg >> 2) + 4 * hi;
            Sw[l31 * 33 + dl] = o[dt][reg];
        }
        const float* src = Sw + q2 * 33 + half * 16;
        u16* dst = opart + (size_t)((ks * 8 + h) * T + qg + q2) * 64 + dt * 32 + half * 16;
        u32 pk[8];
        #pragma unroll
        for (int i = 0; i < 8; i++) pk[i] = pk2bf(src[2 * i], src[2 * i + 1]);
        *(uint4*)(dst)     = make_uint4(pk[0], pk[1], pk[2], pk[3]);
        *(uint4*)(dst + 8) = make_uint4(pk[4], pk[5], pk[6], pk[7]);
    }
    if (hi == 0) ls[(ks * 8 + h) * T + qg + l31] = lsum;
}

// ---------------- kernel 5: merge 8 key-split bf16 partials, normalize, store out ---------
__global__ void k_fin(const u16* __restrict__ opart, const float* __restrict__ ls,
                      void* __restrict__ out, const int* __restrict__ flag) {
    int idx = (blockIdx.x * 256 + threadIdx.x) * 8;   // over [h][t][d] = 2M, grid 1024
    int d0 = idx & 63;
    int ht = idx >> 6;
    int t = ht & (T - 1), h = ht >> 12;
    float lt = 0.f;
    #pragma unroll
    for (int s = 0; s < 8; s++) lt += ls[s * 32768 + ht];
    float inv = 1.0f / lt;
    float v[8] = {};
    #pragma unroll
    for (int s = 0; s < 8; s++) {
        uint4 a = *(const uint4*)(opart + s * 2097152 + idx);
        v[0] += bf2f((u16)(a.x & 0xffff)); v[1] += bf2f((u16)(a.x >> 16));
        v[2] += bf2f((u16)(a.y & 0xffff)); v[3] += bf2f((u16)(a.y >> 16));
        v[4] += bf2f((u16)(a.z & 0xffff)); v[5] += bf2f((u16)(a.z >> 16));
        v[6] += bf2f((u16)(a.w & 0xffff)); v[7] += bf2f((u16)(a.w >> 16));
    }
    #pragma unroll
    for (int i = 0; i < 8; i++) v[i] *= inv;
    int gbase = t * C + h * CH + d0;
    if (*flag) {
        *(float4*)((float*)out + gbase)     = make_float4(v[0], v[1], v[2], v[3]);
        *(float4*)((float*)out + gbase + 4) = make_float4(v[4], v[5], v[6], v[7]);
    } else {
        uint4 o;
        o.x = pk2bf(v[0], v[1]); o.y = pk2bf(v[2], v[3]);
        o.z = pk2bf(v[4], v[5]); o.w = pk2bf(v[6], v[7]);
        *(uint4*)((u16*)out + gbase) = o;
    }
}

extern "C" void kernel_launch(void* const* d_in, const int* in_sizes, int n_in,
                              void* d_out, int out_size, void* d_ws, size_t ws_size,
                              hipStream_t stream) {
    const void* x   = d_in[0];
    const void* gsc = d_in[1];
    const void* gbi = d_in[2];
    const void* wq  = d_in[3];
    const void* bq  = d_in[4];
    char* ws = (char*)d_ws;
    int*   flag = (int*)ws;                          // 4 B
    char* base = ws + 8192;
    u16* qh = (u16*)(base);                          // 4 MB
    u16* kh = (u16*)(base + 4194304);                // 4 MB
    u16* vt = (u16*)(base + 8388608);                // 4 MB (sigma key-permuted)
    u16* xn = (u16*)(base + 12582912);               // 4 MB   (dead after k_gemm)
    u16* wt = (u16*)(base + 16777216);               // 1.5 MB (dead after k_gemm)
    u16* opart = (u16*)(base + 12582912);            // 32 MB bf16 (8 splits x 4MB), overlaps xn/wt
    float* ls    = (float*)(base + 46137344);        // 1 MB  (8 splits x [8][4096])
    float* gs2   = (float*)(base + 47185920);        // 32 KB per-block group partials

    hipLaunchKernelGGL(k_stats1, dim3(128),  dim3(256), 0, stream, x, gs2, flag);
    hipLaunchKernelGGL(k_fuse,   dim3(1280), dim3(256), 0, stream, x, gs2, gsc, gbi, wq, xn, wt, flag);
    hipLaunchKernelGGL(k_gemm,   dim3(768),  dim3(256), 0, stream, xn, wt, bq, flag, qh, kh, vt);
    hipLaunchKernelGGL(k_attn,   dim3(2048), dim3(256), 0, stream, qh, kh, vt, opart, ls);
    hipLaunchKernelGGL(k_fin,    dim3(1024), dim3(256), 0, stream, opart, ls, d_out, flag);
}